// Round 8
// baseline (361.730 us; speedup 1.0000x reference)
//
#include <hip/hip_runtime.h>

constexpr float F_Y0     = 0.28209479177387814f;
constexpr float F_CUTOFF = 4.6f;

typedef short short8 __attribute__((ext_vector_type(8)));
typedef float f32x4  __attribute__((ext_vector_type(4)));
typedef float float2v __attribute__((ext_vector_type(2)));

__device__ __forceinline__ float siluf(float v) { return v / (1.0f + __expf(-v)); }

// gfx950 hardware packed fp32->bf16 (RNE): lo = cvt(a), hi = cvt(b)
__device__ __forceinline__ unsigned pk2(float a, float b) {
  unsigned r;
  asm("v_cvt_pk_bf16_f32 %0, %1, %2" : "=v"(r) : "v"(a), "v"(b));
  return r;
}
// extract bf16 half h (0=lo,1=hi) of dword d as fp32
__device__ __forceinline__ float xbf(unsigned d, int h) {
  return __uint_as_float(h ? (d & 0xffff0000u) : (d << 16));
}
// packed fp32 multiply (full-rate VOP3P on CDNA)
__device__ __forceinline__ float2v pkmul2(float2v a, float2v b) {
  float2v d;
  asm("v_pk_mul_f32 %0, %1, %2" : "=v"(d) : "v"(a), "v"(b));
  return d;
}

union FragU { uint4 u; short8 s; };

__device__ __forceinline__ void load16(const float* p, float* r) {
  const float4* p4 = (const float4*)p;
#pragma unroll
  for (int i = 0; i < 4; i++) {
    float4 t = p4[i];
    r[4*i] = t.x; r[4*i+1] = t.y; r[4*i+2] = t.z; r[4*i+3] = t.w;
  }
}
__device__ __forceinline__ void store16(float* p, const float* r) {
  float4* p4 = (float4*)p;
#pragma unroll
  for (int i = 0; i < 4; i++) p4[i] = make_float4(r[4*i], r[4*i+1], r[4*i+2], r[4*i+3]);
}

// block-level sum of one float per thread -> part[blockIdx.x]
__device__ __forceinline__ void block_reduce_store(float v, float* part) {
  __shared__ float sred[4];
  int tid = threadIdx.x;
#pragma unroll
  for (int off = 32; off > 0; off >>= 1) v += __shfl_down(v, off, 64);
  if ((tid & 63) == 0) sred[tid >> 6] = v;
  __syncthreads();
  if (tid == 0) part[blockIdx.x] = sred[0] + sred[1] + sred[2] + sred[3];
}

// ---------------- fused: per-edge precompute + node init + weight prepack ---
// Block roles by blockIdx.x: [0,nblk_e) edge work; [nblk_e,nblk_e+nblk_n)
// node init; rest prepack. Roles are block-uniform (no divergent barriers).
// Dead-edge compaction: liveness predicate (sc > 0) must be IDENTICAL to
// k_scatter_perm's.
__global__ __launch_bounds__(256) void k_pre(
    const int* __restrict__ species, const int* __restrict__ src, const int* __restrict__ dst,
    const float* __restrict__ rel_pos,
    float* __restrict__ dist_, float* __restrict__ scale_,
    int* __restrict__ cnt,
    float* __restrict__ coul_part,
    int* __restrict__ srcP, float* __restrict__ distP, float* __restrict__ scaleP,
    int E, int nblk_e, int nblk_n,
    const float* __restrict__ emb, const float* __restrict__ Wq0,
    float* __restrict__ x, float* __restrict__ q, int N,
    const float* __restrict__ kv_W3, const float* __restrict__ kv_b3,
    const float* __restrict__ fin_W3, const float* __restrict__ fin_b3,
    const float* __restrict__ kv_W2, const float* __restrict__ fin_W2,
    const float* __restrict__ kv_W1, const float* __restrict__ fin_W1,
    uint4* __restrict__ WF)
{
  int b = blockIdx.x;
  int tid = threadIdx.x;

  if (b >= nblk_e) {
    if (b < nblk_e + nblk_n) {
      // ---- node init role ----
      int n = (b - nblk_e) * 256 + tid;
      if (n >= N) return;
      int sp = species[n] - 1;
      float xv[16];
      load16(emb + (size_t)sp * 16, xv);
      store16(x + (size_t)n * 16, xv);
      float qv[8];
#pragma unroll
      for (int h = 0; h < 8; h++) {
        float a = 0.f;
#pragma unroll
        for (int i = 0; i < 16; i++) a += Wq0[h * 16 + i] * xv[i];
        qv[h] = a;
      }
      float4* qp = (float4*)(q + (size_t)n * 8);
      qp[0] = make_float4(qv[0], qv[1], qv[2], qv[3]);
      qp[1] = make_float4(qv[4], qv[5], qv[6], qv[7]);
    } else {
      // ---- weight prepack role: per layer 21 bf16 B-fragments ----
      // W2 fragments (f=17,18) k-interleaved: physical k position p holds
      // logical row m(p) = (p&1) ? 16+(p>>1) : (p>>1).
      int t = (b - nblk_e - nblk_n) * 256 + tid;
      if (t >= 5 * 21 * 64) return;
      int lyr = t / (21 * 64);
      int rem = t - lyr * 21 * 64;
      int f = rem >> 6;
      int l = rem & 63;
      int qq = l >> 4;
      int o = l & 15;
      const float* W3 = (lyr < 4) ? (kv_W3 + (size_t)lyr * 32 * 256) : fin_W3;
      const float* B3 = (lyr < 4) ? (kv_b3 + (size_t)lyr * 256) : fin_b3;
      const float* W2 = (lyr < 4) ? (kv_W2 + (size_t)lyr * 32 * 32) : fin_W2;
      const float* W1 = (lyr < 4) ? (kv_W1 + (size_t)lyr * 16 * 32) : fin_W1;
      float v[8];
#pragma unroll
      for (int j = 0; j < 8; j++) {
        if (f < 16) {
          int kk = f * 32 + qq * 8 + j;
          int m = kk >> 4, i = kk & 15;
          v[j] = W3[m * 256 + o * 16 + i];
        } else if (f == 16) {
          int r = qq * 8 + j;
          int mp = r >> 4, i = r & 15;
          v[j] = mp ? 0.0f : B3[o * 16 + i];
        } else if (f < 19) {
          int c = f - 17;
          int p = qq * 8 + j;
          int m = (p & 1) ? (16 + (p >> 1)) : (p >> 1);
          v[j] = W2[m * 32 + c * 16 + o];
        } else {
          int c = f - 19;
          int k = qq * 8 + j;
          v[j] = (k < 16) ? W1[k * 32 + c * 16 + o] : 0.0f;
        }
      }
      uint4 dw;
      dw.x = pk2(v[0], v[1]);
      dw.y = pk2(v[2], v[3]);
      dw.z = pk2(v[4], v[5]);
      dw.w = pk2(v[6], v[7]);
      WF[t] = dw;
    }
    return;
  }

  // ---- edge role ----
  __shared__ float zpow[128];
  if (tid < 128) zpow[tid] = __powf((float)tid, 0.23f);
  __syncthreads();

  int e = b * 256 + tid;
  float ce = 0.0f;
  if (e < E) {
    float px = rel_pos[3*(size_t)e + 0];
    float py = rel_pos[3*(size_t)e + 1];
    float pz = rel_pos[3*(size_t)e + 2];
    float dist = sqrtf(px*px + py*py + pz*pz);
    float xc = dist * (1.0f / F_CUTOFF);
    bool in_cut = dist < F_CUTOFF;
    float x2 = in_cut ? xc * xc : 0.0f;
    x2 = fminf(x2, 1.0f - 1e-6f);
    float sc = in_cut ? __expf(3.0f - 3.0f / (1.0f - x2)) : 0.0f;
    dist_[e] = dist;
    scale_[e] = sc;
    srcP[e]   = 0;        // pad defaults (safe reads for straddling tiles)
    distP[e]  = 1.0f;
    scaleP[e] = 0.0f;
    if (sc > 0.0f) {      // SAME predicate as k_scatter_perm
      atomicAdd(&cnt[dst[e]], 1);
      int spu = species[src[e]], spv = species[dst[e]];
      float Zu = (float)spu;
      float Zv = (float)spv;
      float raw = 0.529f * Zu * Zv / (2.0f * dist);
      float au = 0.8854f * 0.529f / (zpow[spu] + zpow[spv]);
      float xx = dist / au;
      float screen = 0.1818f   * __expf(-3.2f    * xx)
                   + 0.5099f   * __expf(-0.9423f * xx)
                   + 0.2802f   * __expf(-0.4028f * xx)
                   + 0.02817f  * __expf(-0.2016f * xx);
      ce = raw * screen * sc;
    }
  }
  block_reduce_store(ce, coul_part);
}

// ---------------- CSR scans ----------------
__global__ __launch_bounds__(256) void k_scan1(
    const int* __restrict__ cnt, int* __restrict__ row_ptr, int* __restrict__ bsum)
{
  __shared__ int s[256];
  int tid = threadIdx.x;
  int n = blockIdx.x * 256 + tid;
  int v = cnt[n];
  s[tid] = v;
  __syncthreads();
#pragma unroll
  for (int off = 1; off < 256; off <<= 1) {
    int t = (tid >= off) ? s[tid - off] : 0;
    __syncthreads();
    s[tid] += t;
    __syncthreads();
  }
  row_ptr[n] = s[tid] - v;
  if (tid == 255) bsum[blockIdx.x] = s[255];
}

// scan3 with scan2 folded in: each block locally scans the 128-entry bsum.
__global__ __launch_bounds__(256) void k_scan3(
    int* __restrict__ row_ptr, int* __restrict__ row_cur,
    const int* __restrict__ bsum, const int* __restrict__ cnt, int N)
{
  __shared__ int sb[128];
  __shared__ int boffv;
  int tid = threadIdx.x;
  if (tid < 128) sb[tid] = bsum[tid];
  __syncthreads();
#pragma unroll
  for (int off = 1; off < 128; off <<= 1) {
    int t = (tid < 128 && tid >= off) ? sb[tid - off] : 0;
    __syncthreads();
    if (tid < 128) sb[tid] += t;
    __syncthreads();
  }
  if (tid == 0) boffv = (blockIdx.x == 0) ? 0 : sb[blockIdx.x - 1];
  __syncthreads();
  int n = blockIdx.x * 256 + tid;
  int rp = row_ptr[n] + boffv;
  row_ptr[n] = rp;
  row_cur[n] = rp;
  if (n == N - 1) row_ptr[N] = rp + cnt[n];   // = E_act (live edges)
}

__global__ __launch_bounds__(256) void k_scatter_perm(
    const int* __restrict__ dst, const float* __restrict__ scale_,
    int* __restrict__ row_cur,
    int* __restrict__ perm, int E)
{
  int e = blockIdx.x * 256 + threadIdx.x;
  if (e >= E) return;
  if (scale_[e] > 0.0f) {
    int pos = atomicAdd(&row_cur[dst[e]], 1);
    perm[pos] = e;
  }
}

__global__ __launch_bounds__(256) void k_permute(
    const int* __restrict__ perm,
    const int* __restrict__ src, const float* __restrict__ dist_, const float* __restrict__ scale_,
    int* __restrict__ srcP, float* __restrict__ distP, float* __restrict__ scaleP,
    const int* __restrict__ eactp)
{
  int i = blockIdx.x * 256 + threadIdx.x;
  if (i >= eactp[0]) return;
  int e = perm[i];
  srcP[i]   = src[e];
  distP[i]  = dist_[e];
  scaleP[i] = scale_[e];
}

// ---------------- heavy edge conv: WAVE-LOCAL, zero __syncthreads ----------
// (unchanged from round 7 — register-built A-fragments, channel-permuted h2)
template <int MODE>
__global__ __launch_bounds__(256, 7) void k_edge_conv(
    const int* __restrict__ srcP,
    const float* __restrict__ scaleP, const float* __restrict__ distP,
    const float* __restrict__ xsum, const float* __restrict__ x,
    const float* __restrict__ W1, const float* __restrict__ B1,
    const float* __restrict__ B2,
    const uint4* __restrict__ WF,
    unsigned* __restrict__ kvB, const int* __restrict__ eactp)
{
  if (blockIdx.x * 64 >= eactp[0]) return;
  __shared__ unsigned smem[4 * 1344];
  int tid = threadIdx.x;
  int w = __builtin_amdgcn_readfirstlane(tid >> 6);
  int l = tid & 63;
  int quad = l >> 4;
  int lo = l & 15;
  unsigned* WS  = smem + w * 1344;     // per-wave private region (5376 B)
  float*    xsS = (float*)WS;          // [0,320)    16 x 20 f32 x[src]
  unsigned* xsB = WS + 320;            // [320,512)  16 x 12 (8 used) bf16 pairs x
  unsigned* efB = WS + 512;            // [512,704)  16 x 12 bf16 pairs ef
  unsigned* h1P = WS + 704;            // [704,1024) 16 x 20 (16 used) pairs (m,m+16)
  unsigned* h2P = WS + 1024;           // [1024,1344) channel-permuted pairs / f32 kv stage

  int ebw = blockIdx.x * 64 + w * 16;

  float b2a = B2[lo], b2b = B2[16 + lo];
  float scv[4];
#pragma unroll
  for (int r = 0; r < 4; r++) scv[r] = scaleP[ebw + quad * 4 + r];

  {
    int e4 = l >> 2, c4 = l & 3;
    int s4 = srcP[ebw + e4];
    float4 xv4 = ((const float4*)(x + (size_t)s4 * 16))[c4];
    float4 ev4;
    if (MODE == 2) {
      ev4 = ((const float4*)(xsum + (size_t)s4 * 16))[c4];
      if (c4 == 3) ev4.w += distP[ebw + e4];
    }
    *(float4*)&xsS[e4 * 20 + c4 * 4] = xv4;
    uint2 xp; xp.x = pk2(xv4.x, xv4.y); xp.y = pk2(xv4.z, xv4.w);
    *(uint2*)&xsB[e4 * 12 + c4 * 2] = xp;
    if (MODE == 2) {
      uint2 ep; ep.x = pk2(ev4.x, ev4.y); ep.y = pk2(ev4.z, ev4.w);
      *(uint2*)&efB[e4 * 12 + c4 * 2] = ep;
    }
  }

  if (MODE == 0) {
    float dd = distP[ebw + lo];
#pragma unroll
    for (int jj = 0; jj < 4; jj++) {
      int d = quad * 4 + jj;
      float v0 = fmaxf(B1[d]      + dd * W1[15 * 32 + d],      0.f);
      float v1 = fmaxf(B1[d + 16] + dd * W1[15 * 32 + d + 16], 0.f);
      h1P[lo * 20 + d] = pk2(v0, v1);
    }
  } else {
    float b1a = B1[lo], b1b = B1[16 + lo];
    FragU a, b0, b1;
    uint4 r = *(const uint4*)&efB[lo * 12 + (quad & 1) * 4];
    uint4 z = make_uint4(0, 0, 0, 0);
    a.u = (quad >= 2) ? z : r;
    b0.u = WF[19 * 64 + l];
    b1.u = WF[20 * 64 + l];
    f32x4 c0 = {0.f, 0.f, 0.f, 0.f};
    f32x4 c1 = {0.f, 0.f, 0.f, 0.f};
    c0 = __builtin_amdgcn_mfma_f32_16x16x32_bf16(a.s, b0.s, c0, 0, 0, 0);
    c1 = __builtin_amdgcn_mfma_f32_16x16x32_bf16(a.s, b1.s, c1, 0, 0, 0);
#pragma unroll
    for (int r2 = 0; r2 < 4; r2++)
      h1P[(quad * 4 + r2) * 20 + lo] =
          pk2(fmaxf(c0[r2] + b1a, 0.f), fmaxf(c1[r2] + b1b, 0.f));
  }

  {
    FragU a, b0, b1;
    a.u = *(const uint4*)&h1P[lo * 20 + quad * 4];
    b0.u = WF[17 * 64 + l];
    b1.u = WF[18 * 64 + l];
    f32x4 hc0 = {0.f, 0.f, 0.f, 0.f};
    f32x4 hc1 = {0.f, 0.f, 0.f, 0.f};
    hc0 = __builtin_amdgcn_mfma_f32_16x16x32_bf16(a.s, b0.s, hc0, 0, 0, 0);
    hc1 = __builtin_amdgcn_mfma_f32_16x16x32_bf16(a.s, b1.s, hc1, 0, 0, 0);
    int pp = (lo & 1) * 8 + (lo >> 1);   // permuted position for channel c=lo
    float b2av = b2a, b2bv = b2b;
#pragma unroll
    for (int r = 0; r < 4; r++)
      h2P[(quad * 4 + r) * 20 + pp] =
          pk2(fmaxf(hc0[r] + b2av, 0.f), fmaxf(hc1[r] + b2bv, 0.f));
  }

  float2v xs2[4];
  {
    const float4* xr = (const float4*)&xsS[lo * 20 + (quad & 1) * 8];
#pragma unroll
    for (int i = 0; i < 2; i++) {
      float4 t = xr[i];
      float2v a; a.x = t.x; a.y = t.y;
      float2v b; b.x = t.z; b.y = t.w;
      xs2[2 * i]     = a;
      xs2[2 * i + 1] = b;
    }
  }
  uint4 hq0 = *(const uint4*)&h2P[lo * 20 + (quad >> 1) * 8];
  uint4 hq1 = *(const uint4*)&h2P[lo * 20 + (quad >> 1) * 8 + 4];
  unsigned hdw[8] = {hq0.x, hq0.y, hq0.z, hq0.w, hq1.x, hq1.y, hq1.z, hq1.w};

  f32x4 acc = {0.f, 0.f, 0.f, 0.f};
  {
    FragU a, b;
    uint4 r = *(const uint4*)&xsB[lo * 12 + (quad & 1) * 4];
    uint4 z = make_uint4(0, 0, 0, 0);
    a.u = (quad >= 2) ? z : r;
    b.u = WF[16 * 64 + l];
    acc = __builtin_amdgcn_mfma_f32_16x16x32_bf16(a.s, b.s, acc, 0, 0, 0);
  }

#pragma unroll
  for (int f = 0; f < 16; f++) {
    float hm = xbf(hdw[f & 7], f >> 3);
    float2v hm2; hm2.x = hm; hm2.y = hm;
    float2v p0 = pkmul2(hm2, xs2[0]);
    float2v p1 = pkmul2(hm2, xs2[1]);
    float2v p2 = pkmul2(hm2, xs2[2]);
    float2v p3 = pkmul2(hm2, xs2[3]);
    FragU a, b;
    a.u.x = pk2(p0.x, p0.y);
    a.u.y = pk2(p1.x, p1.y);
    a.u.z = pk2(p2.x, p2.y);
    a.u.w = pk2(p3.x, p3.y);
    b.u = WF[f * 64 + l];
    acc = __builtin_amdgcn_mfma_f32_16x16x32_bf16(a.s, b.s, acc, 0, 0, 0);
  }

#pragma unroll
  for (int r = 0; r < 4; r++) {
    int e = quad * 4 + r;
    ((float*)h2P)[e * 20 + lo] = acc[r] * (F_Y0 * scv[r]);
  }
  {
    int e2 = l >> 2, c = l & 3;
    const float* row = (const float*)&h2P[e2 * 20 + c * 4];
    float4 t = *(const float4*)row;
    uint2 pkd;
    pkd.x = pk2(t.x, t.y);
    pkd.y = pk2(t.z, t.w);
    *(uint2*)(kvB + ((size_t)(ebw + e2) * 8 + c * 2)) = pkd;
  }
}

// ---------------- fused softmax-gather + node update: 32 threads/node ------
// Each node's 32 workers (h = head, p = edge phase 0..3) live inside ONE
// 32-lane half-wave: every LDS hand-off (sA/sX/sN) is intra-wave, so NO
// __syncthreads is needed (same issue-order argument as k_edge_conv).
// 2x gather parallelism vs 16-thread version; unroll-2 keeps 6 loads in
// flight per thread.
template <bool INIT>
__global__ __launch_bounds__(256) void k_agg_update(
    const int* __restrict__ row_ptr, const float* __restrict__ scaleP,
    const unsigned* __restrict__ kvB, const float* __restrict__ qin,
    const float* __restrict__ xin,
    const float* __restrict__ Wproj, const float* __restrict__ Wq_next,
    float* __restrict__ xout, float* __restrict__ qout, float* __restrict__ xsum, int N)
{
  __shared__ float sA[8 * 8];
  __shared__ float sX[8 * 16];
  __shared__ float sN[8 * 16];
  int tid = threadIdx.x;
  int nl = tid >> 5;          // 8 nodes/block, 2 nodes/wave
  int t32 = tid & 31;
  int h = t32 & 7;
  int p = t32 >> 3;           // 0..3
  int n = blockIdx.x * 8 + nl;
  int hd = h >> 1, hh = h & 1;

  if (t32 < 16) sX[nl * 16 + t32] = xin[(size_t)n * 16 + t32];

  float qh = qin[(size_t)n * 8 + h];
  int j0 = row_ptr[n], j1 = row_ptr[n + 1];
  float num = 0.f, den = 0.f;
  int j = j0 + p;
  for (; j + 4 < j1; j += 8) {
    unsigned va = kvB[(size_t)j * 8 + hd];
    unsigned ka = kvB[(size_t)j * 8 + 4 + hd];
    unsigned vb = kvB[(size_t)(j + 4) * 8 + hd];
    unsigned kb = kvB[(size_t)(j + 4) * 8 + 4 + hd];
    float sa = scaleP[j];
    float sb = scaleP[j + 4];
    float wa = sa * __expf(fminf(xbf(ka, hh) * qh, 60.0f));
    float wb = sb * __expf(fminf(xbf(kb, hh) * qh, 60.0f));
    num += wa * xbf(va, hh) + wb * xbf(vb, hh);
    den += wa + wb;
  }
  for (; j < j1; j += 4) {
    float val = xbf(kvB[(size_t)j * 8 + hd], hh);
    float key = xbf(kvB[(size_t)j * 8 + 4 + hd], hh);
    float wv = scaleP[j] * __expf(fminf(key * qh, 60.0f));
    num += wv * val;
    den += wv;
  }
  num += __shfl_xor(num, 8, 64);  den += __shfl_xor(den, 8, 64);
  num += __shfl_xor(num, 16, 64); den += __shfl_xor(den, 16, 64);
  if (p == 0) sA[nl * 8 + h] = num / fmaxf(den, 1e-20f);

  if (t32 < 16) {
    float cat[24];
#pragma unroll
    for (int jj = 0; jj < 8; jj++) cat[jj] = sA[nl * 8 + jj];
#pragma unroll
    for (int jj = 0; jj < 16; jj++) cat[8 + jj] = sX[nl * 16 + jj];
    float xn = 0.f;
#pragma unroll
    for (int jj = 0; jj < 24; jj++) xn += Wproj[t32 * 24 + jj] * cat[jj];
    xout[(size_t)n * 16 + t32] = xn;
    if (INIT) {
      xsum[(size_t)n * 16 + t32] = xn;
    } else {
      xsum[(size_t)n * 16 + t32] += xn;
    }
    sN[nl * 16 + t32] = xn;
  }
  if (t32 < 8) {
    float a = 0.f;
#pragma unroll
    for (int i = 0; i < 16; i++) a += Wq_next[h * 16 + i] * sN[nl * 16 + i];
    qout[(size_t)n * 8 + h] = a;
  }
}

// ---------------- fused feats gather + final MLP (16 threads/node) ----------
// All per-node LDS traffic is intra-wave (4 nodes/wave, disjoint slices):
// the stage barriers are removed; only block_reduce_store's barrier remains.
__global__ __launch_bounds__(256) void k_feats_final(
    const int* __restrict__ row_ptr, const unsigned* __restrict__ kvB,
    const float* __restrict__ x,
    const int* __restrict__ species, const float* __restrict__ emb,
    const float* __restrict__ Wself,
    const float* __restrict__ mW1, const float* __restrict__ mb1,
    const float* __restrict__ mW2, const float* __restrict__ mb2,
    const float* __restrict__ mW3, const float* __restrict__ mb3,
    float* __restrict__ learn_part, int N)
{
  __shared__ float sX[16 * 20];
  __shared__ float sC[16 * 40];
  __shared__ float sH[16 * 20];
  int tid = threadIdx.x;
  int nl = tid >> 4;
  int o = tid & 15;
  int n = blockIdx.x * 16 + nl;
  int od = o >> 1, oh = o & 1;

  int j0 = row_ptr[n], j1 = row_ptr[n + 1];
  float ft = 0.f;
  int j = j0;
  for (; j + 3 < j1; j += 4) {
    unsigned a = kvB[(size_t)j * 8 + od];
    unsigned b = kvB[(size_t)(j + 1) * 8 + od];
    unsigned c = kvB[(size_t)(j + 2) * 8 + od];
    unsigned d = kvB[(size_t)(j + 3) * 8 + od];
    ft += (xbf(a, oh) + xbf(b, oh)) + (xbf(c, oh) + xbf(d, oh));
  }
  for (; j < j1; ++j) ft += xbf(kvB[(size_t)j * 8 + od], oh);

  if (o < 4) {
    float4 v = ((const float4*)(x + (size_t)n * 16))[o];
    *(float4*)&sX[nl * 20 + o * 4] = v;
  } else if (o < 8) {
    int sp = species[n] - 1;
    float4 v = ((const float4*)(emb + (size_t)sp * 16))[o - 4];
    *(float4*)&sC[nl * 40 + (o - 4) * 4] = v;
  }

  float xv[16];
  load16(&sX[nl * 20], xv);
  float a = ft;
#pragma unroll
  for (int i = 0; i < 16; i++) a += Wself[o * 16 + i] * xv[i];
  sC[nl * 40 + 16 + o] = a;

  float cat[32];
  load16(&sC[nl * 40], cat);
  load16(&sC[nl * 40 + 16], cat + 16);
  float hh2 = mb1[o];
#pragma unroll
  for (int k = 0; k < 32; k++) hh2 += cat[k] * mW1[k * 16 + o];
  hh2 = siluf(hh2);
  sH[nl * 20 + o] = hh2;

  float hv[16];
  load16(&sH[nl * 20], hv);
  float h2 = mb2[o];
#pragma unroll
  for (int k = 0; k < 16; k++) h2 += hv[k] * mW2[k * 16 + o];
  h2 = siluf(h2);
  float contrib = h2 * mW3[o] + ((o == 0) ? mb3[0] : 0.f);
  block_reduce_store(contrib, learn_part);
}

// ---------------- final reduction ----------------
__global__ __launch_bounds__(256) void k_finalize(
    const float* __restrict__ coul_part, int nc,
    const float* __restrict__ learn_part, int nl,
    float* __restrict__ out)
{
  __shared__ float sred[4];
  int tid = threadIdx.x;
  float v = 0.f;
  for (int i = tid; i < nc; i += 256) v += coul_part[i];
  for (int i = tid; i < nl; i += 256) v += learn_part[i];
#pragma unroll
  for (int off = 32; off > 0; off >>= 1) v += __shfl_down(v, off, 64);
  if ((tid & 63) == 0) sred[tid >> 6] = v;
  __syncthreads();
  if (tid == 0) out[0] = sred[0] + sred[1] + sred[2] + sred[3];
}

extern "C" void kernel_launch(void* const* d_in, const int* in_sizes, int n_in,
                              void* d_out, int out_size, void* d_ws, size_t ws_size,
                              hipStream_t stream)
{
  const int*   species = (const int*)d_in[0];
  const int*   src     = (const int*)d_in[1];
  const int*   dst     = (const int*)d_in[2];
  const float* rel_pos = (const float*)d_in[3];
  const float* emb     = (const float*)d_in[4];
  const float* kv_W1   = (const float*)d_in[5];
  const float* kv_b1   = (const float*)d_in[6];
  const float* kv_W2   = (const float*)d_in[7];
  const float* kv_b2   = (const float*)d_in[8];
  const float* kv_W3   = (const float*)d_in[9];
  const float* kv_b3   = (const float*)d_in[10];
  const float* Wq      = (const float*)d_in[11];
  const float* Wproj   = (const float*)d_in[12];
  const float* fin_W1  = (const float*)d_in[13];
  const float* fin_b1  = (const float*)d_in[14];
  const float* fin_W2  = (const float*)d_in[15];
  const float* fin_b2  = (const float*)d_in[16];
  const float* fin_W3  = (const float*)d_in[17];
  const float* fin_b3  = (const float*)d_in[18];
  const float* Wself   = (const float*)d_in[19];
  const float* mlp_W1  = (const float*)d_in[20];
  const float* mlp_b1  = (const float*)d_in[21];
  const float* mlp_W2  = (const float*)d_in[22];
  const float* mlp_b2  = (const float*)d_in[23];
  const float* mlp_W3  = (const float*)d_in[24];
  const float* mlp_b3  = (const float*)d_in[25];

  const int N = in_sizes[0];
  const int E = in_sizes[1];
  const int nblk_e = (E + 255) / 256;
  const int nblk_n = (N + 255) / 256;
  const int nblk_f = N / 16;

  char* p = (char*)d_ws;
  auto alloc = [&](size_t bytes) -> void* {
    void* r = (void*)p;
    p += (bytes + 255) & ~(size_t)255;
    return r;
  };
  float*    dist_   = (float*)alloc((size_t)E * 4);
  float*    scale_  = (float*)alloc((size_t)E * 4);
  float*    distP   = (float*)alloc((size_t)E * 4);
  float*    scaleP  = (float*)alloc((size_t)E * 4);
  int*      srcP    = (int*)  alloc((size_t)E * 4);
  int*      perm    = (int*)  alloc((size_t)E * 4);
  unsigned* kvB     = (unsigned*)alloc((size_t)E * 8 * 4);
  float*    xA      = (float*)alloc((size_t)N * 16 * 4);
  float*    xB      = (float*)alloc((size_t)N * 16 * 4);
  float*    xsum    = (float*)alloc((size_t)N * 16 * 4);
  float*    q       = (float*)alloc((size_t)N * 8 * 4);
  int*      cnt     = (int*)  alloc((size_t)N * 4);
  int*      row_ptr = (int*)  alloc((size_t)(N + 1) * 4);
  int*      row_cur = (int*)  alloc((size_t)N * 4);
  int*      bsum    = (int*)  alloc(128 * 4);
  uint4*    WF      = (uint4*)alloc((size_t)5 * 21 * 64 * 16);
  float*    coul_part  = (float*)alloc((size_t)nblk_e * 4);
  float*    learn_part = (float*)alloc((size_t)nblk_f * 4);

  const int* eactp = row_ptr + N;   // row_ptr[N] = number of live edges

  dim3 blk(256);
  dim3 egrid(nblk_e);
  dim3 cgrid(E / 64);
  dim3 ngrid(nblk_n);
  dim3 augrid(N / 8);
  dim3 fgrid(nblk_f);
  const int nblk_w = 27;   // prepack blocks: ceil(5*21*64 / 256)

  hipMemsetAsync(cnt, 0, (size_t)N * 4, stream);

  k_pre<<<dim3(nblk_e + nblk_n + nblk_w), blk, 0, stream>>>(
      species, src, dst, rel_pos, dist_, scale_, cnt, coul_part,
      srcP, distP, scaleP, E, nblk_e, nblk_n,
      emb, Wq, xA, q, N,
      kv_W3, kv_b3, fin_W3, fin_b3, kv_W2, fin_W2, kv_W1, fin_W1, WF);

  k_scan1<<<ngrid, blk, 0, stream>>>(cnt, row_ptr, bsum);
  k_scan3<<<ngrid, blk, 0, stream>>>(row_ptr, row_cur, bsum, cnt, N);
  k_scatter_perm<<<egrid, blk, 0, stream>>>(dst, scale_, row_cur, perm, E);
  k_permute<<<egrid, blk, 0, stream>>>(perm, src, dist_, scale_,
                                       srcP, distP, scaleP, eactp);

  float* xin = xA;
  float* xout = xB;
  for (int l = 0; l < 4; l++) {
    const float* W1 = kv_W1 + (size_t)l * 16 * 32;
    const float* B1 = kv_b1 + (size_t)l * 32;
    const float* B2 = kv_b2 + (size_t)l * 32;
    const uint4* WFl = WF + (size_t)l * 21 * 64;
    const float* Wqn = Wq + (size_t)((l < 3) ? (l + 1) : 0) * 8 * 16;
    if (l == 0) {
      k_edge_conv<0><<<cgrid, blk, 0, stream>>>(srcP, scaleP, distP, xsum, xin,
                                                W1, B1, B2, WFl, kvB, eactp);
    } else {
      k_edge_conv<2><<<cgrid, blk, 0, stream>>>(srcP, scaleP, distP, xsum, xin,
                                                W1, B1, B2, WFl, kvB, eactp);
    }
    if (l == 0) {
      k_agg_update<true><<<augrid, blk, 0, stream>>>(row_ptr, scaleP, kvB, q, xin,
                                                     Wproj, Wqn, xout, q, xsum, N);
    } else {
      k_agg_update<false><<<augrid, blk, 0, stream>>>(row_ptr, scaleP, kvB, q, xin,
                                                      Wproj + (size_t)l * 16 * 24, Wqn,
                                                      xout, q, xsum, N);
    }
    float* tmp = xin; xin = xout; xout = tmp;
  }

  k_edge_conv<2><<<cgrid, blk, 0, stream>>>(srcP, scaleP, distP, xsum, xin,
                                            fin_W1, fin_b1, fin_b2,
                                            WF + (size_t)4 * 21 * 64, kvB, eactp);
  k_feats_final<<<fgrid, blk, 0, stream>>>(row_ptr, kvB, xin, species, emb, Wself,
                                           mlp_W1, mlp_b1, mlp_W2, mlp_b2, mlp_W3, mlp_b3,
                                           learn_part, N);
  k_finalize<<<dim3(1), blk, 0, stream>>>(coul_part, nblk_e, learn_part, nblk_f,
                                          (float*)d_out);
}

// Round 10
// 355.032 us; speedup vs baseline: 1.0189x; 1.0189x over previous
//
#include <hip/hip_runtime.h>

constexpr float F_Y0     = 0.28209479177387814f;
constexpr float F_CUTOFF = 4.6f;

typedef short short8 __attribute__((ext_vector_type(8)));
typedef float f32x4  __attribute__((ext_vector_type(4)));
typedef float float2v __attribute__((ext_vector_type(2)));

__device__ __forceinline__ float siluf(float v) { return v / (1.0f + __expf(-v)); }

// gfx950 hardware packed fp32->bf16 (RNE): lo = cvt(a), hi = cvt(b)
__device__ __forceinline__ unsigned pk2(float a, float b) {
  unsigned r;
  asm("v_cvt_pk_bf16_f32 %0, %1, %2" : "=v"(r) : "v"(a), "v"(b));
  return r;
}
// extract bf16 half h (0=lo,1=hi) of dword d as fp32
__device__ __forceinline__ float xbf(unsigned d, int h) {
  return __uint_as_float(h ? (d & 0xffff0000u) : (d << 16));
}
// packed fp32 multiply (full-rate VOP3P on CDNA)
__device__ __forceinline__ float2v pkmul2(float2v a, float2v b) {
  float2v d;
  asm("v_pk_mul_f32 %0, %1, %2" : "=v"(d) : "v"(a), "v"(b));
  return d;
}

union FragU { uint4 u; short8 s; };

__device__ __forceinline__ void load16(const float* p, float* r) {
  const float4* p4 = (const float4*)p;
#pragma unroll
  for (int i = 0; i < 4; i++) {
    float4 t = p4[i];
    r[4*i] = t.x; r[4*i+1] = t.y; r[4*i+2] = t.z; r[4*i+3] = t.w;
  }
}
__device__ __forceinline__ void store16(float* p, const float* r) {
  float4* p4 = (float4*)p;
#pragma unroll
  for (int i = 0; i < 4; i++) p4[i] = make_float4(r[4*i], r[4*i+1], r[4*i+2], r[4*i+3]);
}

// block-level sum of one float per thread -> part[blockIdx.x]
__device__ __forceinline__ void block_reduce_store(float v, float* part) {
  __shared__ float sred[4];
  int tid = threadIdx.x;
#pragma unroll
  for (int off = 32; off > 0; off >>= 1) v += __shfl_down(v, off, 64);
  if ((tid & 63) == 0) sred[tid >> 6] = v;
  __syncthreads();
  if (tid == 0) part[blockIdx.x] = sred[0] + sred[1] + sred[2] + sred[3];
}

// ---------------- fused: per-edge precompute + node init + weight prepack ---
// comb layout: 32 floats/node = {x[0..15], xsum[0..15]} -> both per-edge
// gathers land in ONE 128B block. Node-init writes the x half only (xsum half
// is first written by agg<INIT>).
// Dead-edge compaction: liveness predicate (sc > 0) must be IDENTICAL to
// k_scatter_perm's.
__global__ __launch_bounds__(256) void k_pre(
    const int* __restrict__ species, const int* __restrict__ src, const int* __restrict__ dst,
    const float* __restrict__ rel_pos,
    float* __restrict__ dist_, float* __restrict__ scale_,
    int* __restrict__ cnt,
    float* __restrict__ coul_part,
    int* __restrict__ srcP, float* __restrict__ distP, float* __restrict__ scaleP,
    int E, int nblk_e, int nblk_n,
    const float* __restrict__ emb, const float* __restrict__ Wq0,
    float* __restrict__ comb, float* __restrict__ q, int N,
    const float* __restrict__ kv_W3, const float* __restrict__ kv_b3,
    const float* __restrict__ fin_W3, const float* __restrict__ fin_b3,
    const float* __restrict__ kv_W2, const float* __restrict__ fin_W2,
    const float* __restrict__ kv_W1, const float* __restrict__ fin_W1,
    uint4* __restrict__ WF)
{
  int b = blockIdx.x;
  int tid = threadIdx.x;

  if (b >= nblk_e) {
    if (b < nblk_e + nblk_n) {
      // ---- node init role ----
      int n = (b - nblk_e) * 256 + tid;
      if (n >= N) return;
      int sp = species[n] - 1;
      float xv[16];
      load16(emb + (size_t)sp * 16, xv);
      store16(comb + (size_t)n * 32, xv);
      float qv[8];
#pragma unroll
      for (int h = 0; h < 8; h++) {
        float a = 0.f;
#pragma unroll
        for (int i = 0; i < 16; i++) a += Wq0[h * 16 + i] * xv[i];
        qv[h] = a;
      }
      float4* qp = (float4*)(q + (size_t)n * 8);
      qp[0] = make_float4(qv[0], qv[1], qv[2], qv[3]);
      qp[1] = make_float4(qv[4], qv[5], qv[6], qv[7]);
    } else {
      // ---- weight prepack role: per layer 21 bf16 B-fragments ----
      // W2 fragments (f=17,18) k-interleaved: physical k position p holds
      // logical row m(p) = (p&1) ? 16+(p>>1) : (p>>1).
      int t = (b - nblk_e - nblk_n) * 256 + tid;
      if (t >= 5 * 21 * 64) return;
      int lyr = t / (21 * 64);
      int rem = t - lyr * 21 * 64;
      int f = rem >> 6;
      int l = rem & 63;
      int qq = l >> 4;
      int o = l & 15;
      const float* W3 = (lyr < 4) ? (kv_W3 + (size_t)lyr * 32 * 256) : fin_W3;
      const float* B3 = (lyr < 4) ? (kv_b3 + (size_t)lyr * 256) : fin_b3;
      const float* W2 = (lyr < 4) ? (kv_W2 + (size_t)lyr * 32 * 32) : fin_W2;
      const float* W1 = (lyr < 4) ? (kv_W1 + (size_t)lyr * 16 * 32) : fin_W1;
      float v[8];
#pragma unroll
      for (int j = 0; j < 8; j++) {
        if (f < 16) {
          int kk = f * 32 + qq * 8 + j;
          int m = kk >> 4, i = kk & 15;
          v[j] = W3[m * 256 + o * 16 + i];
        } else if (f == 16) {
          int r = qq * 8 + j;
          int mp = r >> 4, i = r & 15;
          v[j] = mp ? 0.0f : B3[o * 16 + i];
        } else if (f < 19) {
          int c = f - 17;
          int p = qq * 8 + j;
          int m = (p & 1) ? (16 + (p >> 1)) : (p >> 1);
          v[j] = W2[m * 32 + c * 16 + o];
        } else {
          int c = f - 19;
          int k = qq * 8 + j;
          v[j] = (k < 16) ? W1[k * 32 + c * 16 + o] : 0.0f;
        }
      }
      uint4 dw;
      dw.x = pk2(v[0], v[1]);
      dw.y = pk2(v[2], v[3]);
      dw.z = pk2(v[4], v[5]);
      dw.w = pk2(v[6], v[7]);
      WF[t] = dw;
    }
    return;
  }

  // ---- edge role ----
  __shared__ float zpow[128];
  if (tid < 128) zpow[tid] = __powf((float)tid, 0.23f);
  __syncthreads();

  int e = b * 256 + tid;
  float ce = 0.0f;
  if (e < E) {
    float px = rel_pos[3*(size_t)e + 0];
    float py = rel_pos[3*(size_t)e + 1];
    float pz = rel_pos[3*(size_t)e + 2];
    float dist = sqrtf(px*px + py*py + pz*pz);
    float xc = dist * (1.0f / F_CUTOFF);
    bool in_cut = dist < F_CUTOFF;
    float x2 = in_cut ? xc * xc : 0.0f;
    x2 = fminf(x2, 1.0f - 1e-6f);
    float sc = in_cut ? __expf(3.0f - 3.0f / (1.0f - x2)) : 0.0f;
    dist_[e] = dist;
    scale_[e] = sc;
    srcP[e]   = 0;        // pad defaults (safe reads for straddling tiles)
    distP[e]  = 1.0f;
    scaleP[e] = 0.0f;
    if (sc > 0.0f) {      // SAME predicate as k_scatter_perm
      atomicAdd(&cnt[dst[e]], 1);
      int spu = species[src[e]], spv = species[dst[e]];
      float Zu = (float)spu;
      float Zv = (float)spv;
      float raw = 0.529f * Zu * Zv / (2.0f * dist);
      float au = 0.8854f * 0.529f / (zpow[spu] + zpow[spv]);
      float xx = dist / au;
      float screen = 0.1818f   * __expf(-3.2f    * xx)
                   + 0.5099f   * __expf(-0.9423f * xx)
                   + 0.2802f   * __expf(-0.4028f * xx)
                   + 0.02817f  * __expf(-0.2016f * xx);
      ce = raw * screen * sc;
    }
  }
  block_reduce_store(ce, coul_part);
}

// ---------------- CSR scans ----------------
__global__ __launch_bounds__(256) void k_scan1(
    const int* __restrict__ cnt, int* __restrict__ row_ptr, int* __restrict__ bsum)
{
  __shared__ int s[256];
  int tid = threadIdx.x;
  int n = blockIdx.x * 256 + tid;
  int v = cnt[n];
  s[tid] = v;
  __syncthreads();
#pragma unroll
  for (int off = 1; off < 256; off <<= 1) {
    int t = (tid >= off) ? s[tid - off] : 0;
    __syncthreads();
    s[tid] += t;
    __syncthreads();
  }
  row_ptr[n] = s[tid] - v;
  if (tid == 255) bsum[blockIdx.x] = s[255];
}

// scan3 with scan2 folded in: each block locally scans the 128-entry bsum.
__global__ __launch_bounds__(256) void k_scan3(
    int* __restrict__ row_ptr, int* __restrict__ row_cur,
    const int* __restrict__ bsum, const int* __restrict__ cnt, int N)
{
  __shared__ int sb[128];
  __shared__ int boffv;
  int tid = threadIdx.x;
  if (tid < 128) sb[tid] = bsum[tid];
  __syncthreads();
#pragma unroll
  for (int off = 1; off < 128; off <<= 1) {
    int t = (tid < 128 && tid >= off) ? sb[tid - off] : 0;
    __syncthreads();
    if (tid < 128) sb[tid] += t;
    __syncthreads();
  }
  if (tid == 0) boffv = (blockIdx.x == 0) ? 0 : sb[blockIdx.x - 1];
  __syncthreads();
  int n = blockIdx.x * 256 + tid;
  int rp = row_ptr[n] + boffv;
  row_ptr[n] = rp;
  row_cur[n] = rp;
  if (n == N - 1) row_ptr[N] = rp + cnt[n];   // = E_act (live edges)
}

__global__ __launch_bounds__(256) void k_scatter_perm(
    const int* __restrict__ dst, const float* __restrict__ scale_,
    int* __restrict__ row_cur,
    int* __restrict__ perm, int E)
{
  int e = blockIdx.x * 256 + threadIdx.x;
  if (e >= E) return;
  if (scale_[e] > 0.0f) {
    int pos = atomicAdd(&row_cur[dst[e]], 1);
    perm[pos] = e;
  }
}

__global__ __launch_bounds__(256) void k_permute(
    const int* __restrict__ perm,
    const int* __restrict__ src, const float* __restrict__ dist_, const float* __restrict__ scale_,
    int* __restrict__ srcP, float* __restrict__ distP, float* __restrict__ scaleP,
    const int* __restrict__ eactp)
{
  int i = blockIdx.x * 256 + threadIdx.x;
  if (i >= eactp[0]) return;
  int e = perm[i];
  srcP[i]   = src[e];
  distP[i]  = dist_[e];
  scaleP[i] = scale_[e];
}

// ---------------- heavy edge conv: WAVE-LOCAL, zero __syncthreads ----------
// Register-built A-fragments, channel-permuted h2 (round 7). Gather now
// reads BOTH x and xsum halves from the single comb record (128 B/node):
// one scattered block per edge instead of two independent ones.
template <int MODE>
__global__ __launch_bounds__(256, 7) void k_edge_conv(
    const int* __restrict__ srcP,
    const float* __restrict__ scaleP, const float* __restrict__ distP,
    const float* __restrict__ comb,
    const float* __restrict__ W1, const float* __restrict__ B1,
    const float* __restrict__ B2,
    const uint4* __restrict__ WF,
    unsigned* __restrict__ kvB, const int* __restrict__ eactp)
{
  if (blockIdx.x * 64 >= eactp[0]) return;
  __shared__ unsigned smem[4 * 1344];
  int tid = threadIdx.x;
  int w = __builtin_amdgcn_readfirstlane(tid >> 6);
  int l = tid & 63;
  int quad = l >> 4;
  int lo = l & 15;
  unsigned* WS  = smem + w * 1344;     // per-wave private region (5376 B)
  float*    xsS = (float*)WS;          // [0,320)    16 x 20 f32 x[src]
  unsigned* xsB = WS + 320;            // [320,512)  16 x 12 (8 used) bf16 pairs x
  unsigned* efB = WS + 512;            // [512,704)  16 x 12 bf16 pairs ef
  unsigned* h1P = WS + 704;            // [704,1024) 16 x 20 (16 used) pairs (m,m+16)
  unsigned* h2P = WS + 1024;           // [1024,1344) channel-permuted pairs / f32 kv stage

  int ebw = blockIdx.x * 64 + w * 16;

  float b2a = B2[lo], b2b = B2[16 + lo];
  float scv[4];
#pragma unroll
  for (int r = 0; r < 4; r++) scv[r] = scaleP[ebw + quad * 4 + r];

  {
    int e4 = l >> 2, c4 = l & 3;
    int s4 = srcP[ebw + e4];
    const float4* base = (const float4*)(comb + (size_t)s4 * 32);
    float4 xv4 = base[c4];
    float4 ev4;
    if (MODE == 2) {
      ev4 = base[4 + c4];
      if (c4 == 3) ev4.w += distP[ebw + e4];
    }
    *(float4*)&xsS[e4 * 20 + c4 * 4] = xv4;
    uint2 xp; xp.x = pk2(xv4.x, xv4.y); xp.y = pk2(xv4.z, xv4.w);
    *(uint2*)&xsB[e4 * 12 + c4 * 2] = xp;
    if (MODE == 2) {
      uint2 ep; ep.x = pk2(ev4.x, ev4.y); ep.y = pk2(ev4.z, ev4.w);
      *(uint2*)&efB[e4 * 12 + c4 * 2] = ep;
    }
  }

  if (MODE == 0) {
    float dd = distP[ebw + lo];
#pragma unroll
    for (int jj = 0; jj < 4; jj++) {
      int d = quad * 4 + jj;
      float v0 = fmaxf(B1[d]      + dd * W1[15 * 32 + d],      0.f);
      float v1 = fmaxf(B1[d + 16] + dd * W1[15 * 32 + d + 16], 0.f);
      h1P[lo * 20 + d] = pk2(v0, v1);
    }
  } else {
    float b1a = B1[lo], b1b = B1[16 + lo];
    FragU a, b0, b1;
    uint4 r = *(const uint4*)&efB[lo * 12 + (quad & 1) * 4];
    uint4 z = make_uint4(0, 0, 0, 0);
    a.u = (quad >= 2) ? z : r;
    b0.u = WF[19 * 64 + l];
    b1.u = WF[20 * 64 + l];
    f32x4 c0 = {0.f, 0.f, 0.f, 0.f};
    f32x4 c1 = {0.f, 0.f, 0.f, 0.f};
    c0 = __builtin_amdgcn_mfma_f32_16x16x32_bf16(a.s, b0.s, c0, 0, 0, 0);
    c1 = __builtin_amdgcn_mfma_f32_16x16x32_bf16(a.s, b1.s, c1, 0, 0, 0);
#pragma unroll
    for (int r2 = 0; r2 < 4; r2++)
      h1P[(quad * 4 + r2) * 20 + lo] =
          pk2(fmaxf(c0[r2] + b1a, 0.f), fmaxf(c1[r2] + b1b, 0.f));
  }

  {
    FragU a, b0, b1;
    a.u = *(const uint4*)&h1P[lo * 20 + quad * 4];
    b0.u = WF[17 * 64 + l];
    b1.u = WF[18 * 64 + l];
    f32x4 hc0 = {0.f, 0.f, 0.f, 0.f};
    f32x4 hc1 = {0.f, 0.f, 0.f, 0.f};
    hc0 = __builtin_amdgcn_mfma_f32_16x16x32_bf16(a.s, b0.s, hc0, 0, 0, 0);
    hc1 = __builtin_amdgcn_mfma_f32_16x16x32_bf16(a.s, b1.s, hc1, 0, 0, 0);
    int pp = (lo & 1) * 8 + (lo >> 1);   // permuted position for channel c=lo
    float b2av = b2a, b2bv = b2b;
#pragma unroll
    for (int r = 0; r < 4; r++)
      h2P[(quad * 4 + r) * 20 + pp] =
          pk2(fmaxf(hc0[r] + b2av, 0.f), fmaxf(hc1[r] + b2bv, 0.f));
  }

  float2v xs2[4];
  {
    const float4* xr = (const float4*)&xsS[lo * 20 + (quad & 1) * 8];
#pragma unroll
    for (int i = 0; i < 2; i++) {
      float4 t = xr[i];
      float2v a; a.x = t.x; a.y = t.y;
      float2v b; b.x = t.z; b.y = t.w;
      xs2[2 * i]     = a;
      xs2[2 * i + 1] = b;
    }
  }
  uint4 hq0 = *(const uint4*)&h2P[lo * 20 + (quad >> 1) * 8];
  uint4 hq1 = *(const uint4*)&h2P[lo * 20 + (quad >> 1) * 8 + 4];
  unsigned hdw[8] = {hq0.x, hq0.y, hq0.z, hq0.w, hq1.x, hq1.y, hq1.z, hq1.w};

  f32x4 acc = {0.f, 0.f, 0.f, 0.f};
  {
    FragU a, b;
    uint4 r = *(const uint4*)&xsB[lo * 12 + (quad & 1) * 4];
    uint4 z = make_uint4(0, 0, 0, 0);
    a.u = (quad >= 2) ? z : r;
    b.u = WF[16 * 64 + l];
    acc = __builtin_amdgcn_mfma_f32_16x16x32_bf16(a.s, b.s, acc, 0, 0, 0);
  }

#pragma unroll
  for (int f = 0; f < 16; f++) {
    float hm = xbf(hdw[f & 7], f >> 3);
    float2v hm2; hm2.x = hm; hm2.y = hm;
    float2v p0 = pkmul2(hm2, xs2[0]);
    float2v p1 = pkmul2(hm2, xs2[1]);
    float2v p2 = pkmul2(hm2, xs2[2]);
    float2v p3 = pkmul2(hm2, xs2[3]);
    FragU a, b;
    a.u.x = pk2(p0.x, p0.y);
    a.u.y = pk2(p1.x, p1.y);
    a.u.z = pk2(p2.x, p2.y);
    a.u.w = pk2(p3.x, p3.y);
    b.u = WF[f * 64 + l];
    acc = __builtin_amdgcn_mfma_f32_16x16x32_bf16(a.s, b.s, acc, 0, 0, 0);
  }

#pragma unroll
  for (int r = 0; r < 4; r++) {
    int e = quad * 4 + r;
    ((float*)h2P)[e * 20 + lo] = acc[r] * (F_Y0 * scv[r]);
  }
  {
    int e2 = l >> 2, c = l & 3;
    const float* row = (const float*)&h2P[e2 * 20 + c * 4];
    float4 t = *(const float4*)row;
    uint2 pkd;
    pkd.x = pk2(t.x, t.y);
    pkd.y = pk2(t.z, t.w);
    *(uint2*)(kvB + ((size_t)(ebw + e2) * 8 + c * 2)) = pkd;
  }
}

// ---------------- fused softmax-gather + node update: 32 threads/node ------
// Intra-half-wave LDS hand-offs, no __syncthreads (round 8). Writes BOTH
// halves of the comb out-record: x half = xn, xsum half = comb_in.xsum + xn
// (INIT: = xn). Value chain identical to the old separate-xsum version.
template <bool INIT>
__global__ __launch_bounds__(256) void k_agg_update(
    const int* __restrict__ row_ptr, const float* __restrict__ scaleP,
    const unsigned* __restrict__ kvB, const float* __restrict__ qin,
    const float* __restrict__ comb_in,
    const float* __restrict__ Wproj, const float* __restrict__ Wq_next,
    float* __restrict__ comb_out, float* __restrict__ qout, int N)
{
  __shared__ float sA[8 * 8];
  __shared__ float sX[8 * 16];
  __shared__ float sN[8 * 16];
  int tid = threadIdx.x;
  int nl = tid >> 5;          // 8 nodes/block, 2 nodes/wave
  int t32 = tid & 31;
  int h = t32 & 7;
  int p = t32 >> 3;           // 0..3
  int n = blockIdx.x * 8 + nl;
  int hd = h >> 1, hh = h & 1;

  if (t32 < 16) sX[nl * 16 + t32] = comb_in[(size_t)n * 32 + t32];

  float qh = qin[(size_t)n * 8 + h];
  int j0 = row_ptr[n], j1 = row_ptr[n + 1];
  float num = 0.f, den = 0.f;
  int j = j0 + p;
  for (; j + 4 < j1; j += 8) {
    unsigned va = kvB[(size_t)j * 8 + hd];
    unsigned ka = kvB[(size_t)j * 8 + 4 + hd];
    unsigned vb = kvB[(size_t)(j + 4) * 8 + hd];
    unsigned kb = kvB[(size_t)(j + 4) * 8 + 4 + hd];
    float sa = scaleP[j];
    float sb = scaleP[j + 4];
    float wa = sa * __expf(fminf(xbf(ka, hh) * qh, 60.0f));
    float wb = sb * __expf(fminf(xbf(kb, hh) * qh, 60.0f));
    num += wa * xbf(va, hh) + wb * xbf(vb, hh);
    den += wa + wb;
  }
  for (; j < j1; j += 4) {
    float val = xbf(kvB[(size_t)j * 8 + hd], hh);
    float key = xbf(kvB[(size_t)j * 8 + 4 + hd], hh);
    float wv = scaleP[j] * __expf(fminf(key * qh, 60.0f));
    num += wv * val;
    den += wv;
  }
  num += __shfl_xor(num, 8, 64);  den += __shfl_xor(den, 8, 64);
  num += __shfl_xor(num, 16, 64); den += __shfl_xor(den, 16, 64);
  if (p == 0) sA[nl * 8 + h] = num / fmaxf(den, 1e-20f);

  if (t32 < 16) {
    float cat[24];
#pragma unroll
    for (int jj = 0; jj < 8; jj++) cat[jj] = sA[nl * 8 + jj];
#pragma unroll
    for (int jj = 0; jj < 16; jj++) cat[8 + jj] = sX[nl * 16 + jj];
    float xn = 0.f;
#pragma unroll
    for (int jj = 0; jj < 24; jj++) xn += Wproj[t32 * 24 + jj] * cat[jj];
    comb_out[(size_t)n * 32 + t32] = xn;
    float xs;
    if (INIT) {
      xs = xn;
    } else {
      xs = comb_in[(size_t)n * 32 + 16 + t32] + xn;
    }
    comb_out[(size_t)n * 32 + 16 + t32] = xs;
    sN[nl * 16 + t32] = xn;
  }
  if (t32 < 8) {
    float a = 0.f;
#pragma unroll
    for (int i = 0; i < 16; i++) a += Wq_next[h * 16 + i] * sN[nl * 16 + i];
    qout[(size_t)n * 8 + h] = a;
  }
}

// ---------------- fused feats gather + final MLP (16 threads/node) ----------
// x is read from the comb record's x half (stride 32 floats).
__global__ __launch_bounds__(256) void k_feats_final(
    const int* __restrict__ row_ptr, const unsigned* __restrict__ kvB,
    const float* __restrict__ comb,
    const int* __restrict__ species, const float* __restrict__ emb,
    const float* __restrict__ Wself,
    const float* __restrict__ mW1, const float* __restrict__ mb1,
    const float* __restrict__ mW2, const float* __restrict__ mb2,
    const float* __restrict__ mW3, const float* __restrict__ mb3,
    float* __restrict__ learn_part, int N)
{
  __shared__ float sX[16 * 20];
  __shared__ float sC[16 * 40];
  __shared__ float sH[16 * 20];
  int tid = threadIdx.x;
  int nl = tid >> 4;
  int o = tid & 15;
  int n = blockIdx.x * 16 + nl;
  int od = o >> 1, oh = o & 1;

  int j0 = row_ptr[n], j1 = row_ptr[n + 1];
  float ft = 0.f;
  int j = j0;
  for (; j + 3 < j1; j += 4) {
    unsigned a = kvB[(size_t)j * 8 + od];
    unsigned b = kvB[(size_t)(j + 1) * 8 + od];
    unsigned c = kvB[(size_t)(j + 2) * 8 + od];
    unsigned d = kvB[(size_t)(j + 3) * 8 + od];
    ft += (xbf(a, oh) + xbf(b, oh)) + (xbf(c, oh) + xbf(d, oh));
  }
  for (; j < j1; ++j) ft += xbf(kvB[(size_t)j * 8 + od], oh);

  if (o < 4) {
    float4 v = ((const float4*)(comb + (size_t)n * 32))[o];
    *(float4*)&sX[nl * 20 + o * 4] = v;
  } else if (o < 8) {
    int sp = species[n] - 1;
    float4 v = ((const float4*)(emb + (size_t)sp * 16))[o - 4];
    *(float4*)&sC[nl * 40 + (o - 4) * 4] = v;
  }

  float xv[16];
  load16(&sX[nl * 20], xv);
  float a = ft;
#pragma unroll
  for (int i = 0; i < 16; i++) a += Wself[o * 16 + i] * xv[i];
  sC[nl * 40 + 16 + o] = a;

  float cat[32];
  load16(&sC[nl * 40], cat);
  load16(&sC[nl * 40 + 16], cat + 16);
  float hh2 = mb1[o];
#pragma unroll
  for (int k = 0; k < 32; k++) hh2 += cat[k] * mW1[k * 16 + o];
  hh2 = siluf(hh2);
  sH[nl * 20 + o] = hh2;

  float hv[16];
  load16(&sH[nl * 20], hv);
  float h2 = mb2[o];
#pragma unroll
  for (int k = 0; k < 16; k++) h2 += hv[k] * mW2[k * 16 + o];
  h2 = siluf(h2);
  float contrib = h2 * mW3[o] + ((o == 0) ? mb3[0] : 0.f);
  block_reduce_store(contrib, learn_part);
}

// ---------------- final reduction ----------------
__global__ __launch_bounds__(256) void k_finalize(
    const float* __restrict__ coul_part, int nc,
    const float* __restrict__ learn_part, int nl,
    float* __restrict__ out)
{
  __shared__ float sred[4];
  int tid = threadIdx.x;
  float v = 0.f;
  for (int i = tid; i < nc; i += 256) v += coul_part[i];
  for (int i = tid; i < nl; i += 256) v += learn_part[i];
#pragma unroll
  for (int off = 32; off > 0; off >>= 1) v += __shfl_down(v, off, 64);
  if ((tid & 63) == 0) sred[tid >> 6] = v;
  __syncthreads();
  if (tid == 0) out[0] = sred[0] + sred[1] + sred[2] + sred[3];
}

extern "C" void kernel_launch(void* const* d_in, const int* in_sizes, int n_in,
                              void* d_out, int out_size, void* d_ws, size_t ws_size,
                              hipStream_t stream)
{
  const int*   species = (const int*)d_in[0];
  const int*   src     = (const int*)d_in[1];
  const int*   dst     = (const int*)d_in[2];
  const float* rel_pos = (const float*)d_in[3];
  const float* emb     = (const float*)d_in[4];
  const float* kv_W1   = (const float*)d_in[5];
  const float* kv_b1   = (const float*)d_in[6];
  const float* kv_W2   = (const float*)d_in[7];
  const float* kv_b2   = (const float*)d_in[8];
  const float* kv_W3   = (const float*)d_in[9];
  const float* kv_b3   = (const float*)d_in[10];
  const float* Wq      = (const float*)d_in[11];
  const float* Wproj   = (const float*)d_in[12];
  const float* fin_W1  = (const float*)d_in[13];
  const float* fin_b1  = (const float*)d_in[14];
  const float* fin_W2  = (const float*)d_in[15];
  const float* fin_b2  = (const float*)d_in[16];
  const float* fin_W3  = (const float*)d_in[17];
  const float* fin_b3  = (const float*)d_in[18];
  const float* Wself   = (const float*)d_in[19];
  const float* mlp_W1  = (const float*)d_in[20];
  const float* mlp_b1  = (const float*)d_in[21];
  const float* mlp_W2  = (const float*)d_in[22];
  const float* mlp_b2  = (const float*)d_in[23];
  const float* mlp_W3  = (const float*)d_in[24];
  const float* mlp_b3  = (const float*)d_in[25];

  const int N = in_sizes[0];
  const int E = in_sizes[1];
  const int nblk_e = (E + 255) / 256;
  const int nblk_n = (N + 255) / 256;
  const int nblk_f = N / 16;

  char* p = (char*)d_ws;
  auto alloc = [&](size_t bytes) -> void* {
    void* r = (void*)p;
    p += (bytes + 255) & ~(size_t)255;
    return r;
  };
  float*    dist_   = (float*)alloc((size_t)E * 4);
  float*    scale_  = (float*)alloc((size_t)E * 4);
  float*    distP   = (float*)alloc((size_t)E * 4);
  float*    scaleP  = (float*)alloc((size_t)E * 4);
  int*      srcP    = (int*)  alloc((size_t)E * 4);
  int*      perm    = (int*)  alloc((size_t)E * 4);
  unsigned* kvB     = (unsigned*)alloc((size_t)E * 8 * 4);
  float*    combA   = (float*)alloc((size_t)N * 32 * 4);
  float*    combB   = (float*)alloc((size_t)N * 32 * 4);
  float*    q       = (float*)alloc((size_t)N * 8 * 4);
  int*      cnt     = (int*)  alloc((size_t)N * 4);
  int*      row_ptr = (int*)  alloc((size_t)(N + 1) * 4);
  int*      row_cur = (int*)  alloc((size_t)N * 4);
  int*      bsum    = (int*)  alloc(128 * 4);
  uint4*    WF      = (uint4*)alloc((size_t)5 * 21 * 64 * 16);
  float*    coul_part  = (float*)alloc((size_t)nblk_e * 4);
  float*    learn_part = (float*)alloc((size_t)nblk_f * 4);

  const int* eactp = row_ptr + N;   // row_ptr[N] = number of live edges

  dim3 blk(256);
  dim3 egrid(nblk_e);
  dim3 cgrid(E / 64);
  dim3 ngrid(nblk_n);
  dim3 augrid(N / 8);
  dim3 fgrid(nblk_f);
  const int nblk_w = 27;   // prepack blocks: ceil(5*21*64 / 256)

  hipMemsetAsync(cnt, 0, (size_t)N * 4, stream);

  k_pre<<<dim3(nblk_e + nblk_n + nblk_w), blk, 0, stream>>>(
      species, src, dst, rel_pos, dist_, scale_, cnt, coul_part,
      srcP, distP, scaleP, E, nblk_e, nblk_n,
      emb, Wq, combA, q, N,
      kv_W3, kv_b3, fin_W3, fin_b3, kv_W2, fin_W2, kv_W1, fin_W1, WF);

  k_scan1<<<ngrid, blk, 0, stream>>>(cnt, row_ptr, bsum);
  k_scan3<<<ngrid, blk, 0, stream>>>(row_ptr, row_cur, bsum, cnt, N);
  k_scatter_perm<<<egrid, blk, 0, stream>>>(dst, scale_, row_cur, perm, E);
  k_permute<<<egrid, blk, 0, stream>>>(perm, src, dist_, scale_,
                                       srcP, distP, scaleP, eactp);

  float* xin = combA;
  float* xout = combB;
  for (int l = 0; l < 4; l++) {
    const float* W1 = kv_W1 + (size_t)l * 16 * 32;
    const float* B1 = kv_b1 + (size_t)l * 32;
    const float* B2 = kv_b2 + (size_t)l * 32;
    const uint4* WFl = WF + (size_t)l * 21 * 64;
    const float* Wqn = Wq + (size_t)((l < 3) ? (l + 1) : 0) * 8 * 16;
    if (l == 0) {
      k_edge_conv<0><<<cgrid, blk, 0, stream>>>(srcP, scaleP, distP, xin,
                                                W1, B1, B2, WFl, kvB, eactp);
    } else {
      k_edge_conv<2><<<cgrid, blk, 0, stream>>>(srcP, scaleP, distP, xin,
                                                W1, B1, B2, WFl, kvB, eactp);
    }
    if (l == 0) {
      k_agg_update<true><<<augrid, blk, 0, stream>>>(row_ptr, scaleP, kvB, q, xin,
                                                     Wproj, Wqn, xout, q, N);
    } else {
      k_agg_update<false><<<augrid, blk, 0, stream>>>(row_ptr, scaleP, kvB, q, xin,
                                                      Wproj + (size_t)l * 16 * 24, Wqn,
                                                      xout, q, N);
    }
    float* tmp = xin; xin = xout; xout = tmp;
  }

  k_edge_conv<2><<<cgrid, blk, 0, stream>>>(srcP, scaleP, distP, xin,
                                            fin_W1, fin_b1, fin_b2,
                                            WF + (size_t)4 * 21 * 64, kvB, eactp);
  k_feats_final<<<fgrid, blk, 0, stream>>>(row_ptr, kvB, xin, species, emb, Wself,
                                           mlp_W1, mlp_b1, mlp_W2, mlp_b2, mlp_W3, mlp_b3,
                                           learn_part, N);
  k_finalize<<<dim3(1), blk, 0, stream>>>(coul_part, nblk_e, learn_part, nblk_f,
                                          (float*)d_out);
}